// Round 2
// baseline (1902.830 us; speedup 1.0000x reference)
//
#include <hip/hip_runtime.h>

typedef __bf16 bf16x8 __attribute__((ext_vector_type(8)));
typedef float  f32x4  __attribute__((ext_vector_type(4)));

#define BATCH 4
#define SEQ 2048
#define DMODEL 1024
#define M_ROWS (BATCH * SEQ)      // 8192

// ---------------------------------------------------------------
// f32 -> (hi, lo) bf16 split:  v ~= hi + lo, |residual| <= 2^-17 |v|
// ---------------------------------------------------------------
__global__ __launch_bounds__(256) void cvt_split(
    const float* __restrict__ src, __bf16* __restrict__ hi,
    __bf16* __restrict__ lo, int n)
{
    const int i = blockIdx.x * 256 + threadIdx.x;
    if (i < n) {
        const float v = src[i];
        const __bf16 h = (__bf16)v;
        hi[i] = h;
        lo[i] = (__bf16)(v - (float)h);
    }
}

__global__ __launch_bounds__(256) void cvt_plain(
    const float* __restrict__ src, __bf16* __restrict__ dst, int n)
{
    const int i = blockIdx.x * 256 + threadIdx.x;
    if (i < n) dst[i] = (__bf16)src[i];
}

// ---------------------------------------------------------------
// Split-precision GEMM: C[m][n] = sum_k A[m][k] * W[n][k], f32-accurate
// via (Ah+Al)·(Wh+Wl) ~= Ah·Wh + Ah·Wl + Al·Wh  (3x mfma bf16).
// Wave tile: 32(M) x 64(N). Block: 4 waves stacked along M -> 128 x 64.
// mfma_f32_16x16x32_bf16 verified layout (m89/m91):
//   A: lane l holds A[m0+(l&15)][k0+(l>>4)*8 + j]
//   B: lane l holds W[n0+(l&15)][k0+(l>>4)*8 + j]
//   D: lane l, reg r -> row m0+(l>>4)*4+r, col n0+(l&15)
// ---------------------------------------------------------------
__global__ __launch_bounds__(256) void gemm_split(
    const __bf16* __restrict__ Ah, const __bf16* __restrict__ Al,
    const __bf16* __restrict__ Bh, const __bf16* __restrict__ Bl,
    float* __restrict__ C, int K, int N)
{
    const int wave = threadIdx.x >> 6;
    const int lane = threadIdx.x & 63;
    const int m0 = blockIdx.y * 128 + wave * 32;
    const int n0 = blockIdx.x * 64;
    const int qk = (lane >> 4) * 8;
    const int r16 = lane & 15;

    f32x4 acc[2][4] = {};

    const size_t a0 = (size_t)(m0 + r16) * K + qk;
    const size_t a1 = a0 + (size_t)16 * K;
    const size_t b0 = (size_t)(n0 + r16) * K + qk;

    for (int k0 = 0; k0 < K; k0 += 32) {
        bf16x8 ah0 = *(const bf16x8*)(Ah + a0 + k0);
        bf16x8 al0 = *(const bf16x8*)(Al + a0 + k0);
        bf16x8 ah1 = *(const bf16x8*)(Ah + a1 + k0);
        bf16x8 al1 = *(const bf16x8*)(Al + a1 + k0);
#pragma unroll
        for (int i = 0; i < 4; ++i) {
            bf16x8 bh = *(const bf16x8*)(Bh + b0 + (size_t)i * 16 * K + k0);
            bf16x8 bl = *(const bf16x8*)(Bl + b0 + (size_t)i * 16 * K + k0);
            acc[0][i] = __builtin_amdgcn_mfma_f32_16x16x32_bf16(al0, bh, acc[0][i], 0, 0, 0);
            acc[0][i] = __builtin_amdgcn_mfma_f32_16x16x32_bf16(ah0, bl, acc[0][i], 0, 0, 0);
            acc[0][i] = __builtin_amdgcn_mfma_f32_16x16x32_bf16(ah0, bh, acc[0][i], 0, 0, 0);
            acc[1][i] = __builtin_amdgcn_mfma_f32_16x16x32_bf16(al1, bh, acc[1][i], 0, 0, 0);
            acc[1][i] = __builtin_amdgcn_mfma_f32_16x16x32_bf16(ah1, bl, acc[1][i], 0, 0, 0);
            acc[1][i] = __builtin_amdgcn_mfma_f32_16x16x32_bf16(ah1, bh, acc[1][i], 0, 0, 0);
        }
    }

    const int r_off = (lane >> 4) * 4;
#pragma unroll
    for (int s = 0; s < 2; ++s)
#pragma unroll
        for (int i = 0; i < 4; ++i)
#pragma unroll
            for (int r = 0; r < 4; ++r)
                C[(size_t)(m0 + s * 16 + r_off + r) * N + n0 + i * 16 + r16] = acc[s][i][r];
}

// ---------------------------------------------------------------
// Plain bf16 GEMM (for the final linear out_proj), f32 output.
// ---------------------------------------------------------------
__global__ __launch_bounds__(256) void gemm_bf16(
    const __bf16* __restrict__ A, const __bf16* __restrict__ B,
    float* __restrict__ C, int K, int N)
{
    const int wave = threadIdx.x >> 6;
    const int lane = threadIdx.x & 63;
    const int m0 = blockIdx.y * 128 + wave * 32;
    const int n0 = blockIdx.x * 64;
    const int qk = (lane >> 4) * 8;
    const int r16 = lane & 15;

    f32x4 acc[2][4] = {};
    const size_t a0 = (size_t)(m0 + r16) * K + qk;
    const size_t a1 = a0 + (size_t)16 * K;
    const size_t b0 = (size_t)(n0 + r16) * K + qk;

    for (int k0 = 0; k0 < K; k0 += 32) {
        bf16x8 av0 = *(const bf16x8*)(A + a0 + k0);
        bf16x8 av1 = *(const bf16x8*)(A + a1 + k0);
#pragma unroll
        for (int i = 0; i < 4; ++i) {
            bf16x8 bv = *(const bf16x8*)(B + b0 + (size_t)i * 16 * K + k0);
            acc[0][i] = __builtin_amdgcn_mfma_f32_16x16x32_bf16(av0, bv, acc[0][i], 0, 0, 0);
            acc[1][i] = __builtin_amdgcn_mfma_f32_16x16x32_bf16(av1, bv, acc[1][i], 0, 0, 0);
        }
    }

    const int r_off = (lane >> 4) * 4;
#pragma unroll
    for (int s = 0; s < 2; ++s)
#pragma unroll
        for (int i = 0; i < 4; ++i)
#pragma unroll
            for (int r = 0; r < 4; ++r)
                C[(size_t)(m0 + s * 16 + r_off + r) * N + n0 + i * 16 + r16] = acc[s][i][r];
}

// ---------------------------------------------------------------
// Depthwise causal conv (width 4) + bias + SiLU, all f32.
// xz: (M, 2048); first 1024 cols are x_ssm. out: x_conv (M,1024).
// ---------------------------------------------------------------
__global__ __launch_bounds__(256) void conv_silu_kernel(
    const float* __restrict__ xz,
    const float* __restrict__ conv_w,
    const float* __restrict__ conv_b,
    float* __restrict__ x_conv)
{
    const int idx = blockIdx.x * 256 + threadIdx.x;   // 0 .. M*1024-1
    const int d = idx & (DMODEL - 1);
    const int m = idx >> 10;
    const int l = m & (SEQ - 1);

    float acc = conv_b[d];
#pragma unroll
    for (int k = 0; k < 4; ++k) {
        const int ll = l + k - 3;
        if (ll >= 0)
            acc += xz[(size_t)(m + k - 3) * 2048 + d] * conv_w[d * 4 + k];
    }
    x_conv[idx] = acc / (1.f + __expf(-acc));   // SiLU
}

// ---------------------------------------------------------------
// x_proj: P[m][e] = sum_d x_conv[m][d] * W[e][d], e in [0,33). f32 VALU.
// One wave per row. softplus on e==32.
// ---------------------------------------------------------------
__global__ __launch_bounds__(256) void xproj_kernel(
    const float* __restrict__ xc,
    const float* __restrict__ W,
    float* __restrict__ P)
{
    const int wave = threadIdx.x >> 6;
    const int lane = threadIdx.x & 63;
    const int row = blockIdx.x * 4 + wave;
    const float* xr = xc + (size_t)row * DMODEL;

    float acc[33];
#pragma unroll
    for (int e = 0; e < 33; ++e) acc[e] = 0.f;

    for (int d = lane; d < DMODEL; d += 64) {
        const float xv = xr[d];
#pragma unroll
        for (int e = 0; e < 33; ++e)
            acc[e] += xv * W[e * DMODEL + d];
    }
#pragma unroll
    for (int e = 0; e < 33; ++e) {
        float v = acc[e];
#pragma unroll
        for (int off = 32; off; off >>= 1) v += __shfl_xor(v, off, 64);
        acc[e] = v;
    }
    if (lane == 0) {
        float* out = P + (size_t)row * 33;
        for (int e = 0; e < 32; ++e) out[e] = acc[e];
        const float x = acc[32];
        out[32] = (x > 20.f) ? x : log1pf(expf(x));
    }
}

// ---------------------------------------------------------------
// Selective scan, f32. One thread per (b,d) channel, h[16] in VGPRs.
// Fuses D-skip + SiLU(z) gating; emits y as bf16 for out_proj.
// Block = 64 threads (1 wave) so the 64 waves spread over 64 CUs.
// ---------------------------------------------------------------
__global__ __launch_bounds__(64) void scan_kernel(
    const float* __restrict__ P,      // (M,33), delta softplus'ed
    const float* __restrict__ xc,     // (M,1024)
    const float* __restrict__ xz,     // (M,2048); z at col 1024+d
    const float* __restrict__ A_log,  // (1024,16)
    const float* __restrict__ Dp,     // (1024)
    __bf16* __restrict__ Y)           // (M,1024)
{
    const int b = blockIdx.x;                      // 0..3
    const int d = blockIdx.y * 64 + threadIdx.x;   // 0..1023

    float Arow[16];
#pragma unroll
    for (int n = 0; n < 16; ++n) Arow[n] = -__expf(A_log[d * 16 + n]);
    const float Dv = Dp[d];

    float h[16];
#pragma unroll
    for (int n = 0; n < 16; ++n) h[n] = 0.f;

    const int CH = 64;
    __shared__ float buf[64 * 33];

    for (int l0 = 0; l0 < SEQ; l0 += CH) {
        __syncthreads();
        const float* src = P + (size_t)(b * SEQ + l0) * 33;
        for (int idx = threadIdx.x; idx < CH * 33; idx += 64)
            buf[idx] = src[idx];
        __syncthreads();

        for (int j = 0; j < CH; ++j) {
            const int m = b * SEQ + l0 + j;
            const float xv = xc[(size_t)m * 1024 + d];
            const float zv = xz[(size_t)m * 2048 + 1024 + d];
            const float* pp = &buf[j * 33];
            const float delta = pp[32];
            const float dx = delta * xv;
            float y = 0.f;
#pragma unroll
            for (int n = 0; n < 16; ++n) {
                const float e = __expf(delta * Arow[n]);
                h[n] = e * h[n] + dx * pp[n];
                y += h[n] * pp[16 + n];
            }
            y += Dv * xv;
            const float sz = zv / (1.f + __expf(-zv));
            Y[(size_t)m * 1024 + d] = (__bf16)(y * sz);
        }
    }
}

// ---------------------------------------------------------------
extern "C" void kernel_launch(void* const* d_in, const int* in_sizes, int n_in,
                              void* d_out, int out_size, void* d_ws, size_t ws_size,
                              hipStream_t stream) {
    const float* x          = (const float*)d_in[0];
    const float* in_proj_w  = (const float*)d_in[1];
    const float* conv_w     = (const float*)d_in[2];
    const float* conv_b     = (const float*)d_in[3];
    const float* x_proj_w   = (const float*)d_in[4];
    const float* A_log      = (const float*)d_in[5];
    const float* D_param    = (const float*)d_in[6];
    const float* out_proj_w = (const float*)d_in[7];
    float* out = (float*)d_out;

    char* ws = (char*)d_ws;
    // live:   [0,64M) xz f32 (after gemm1)
    // phase1: [64M,96M) x_hi/x_lo, [96M,104M) wi_hi/wi_lo  (dead after gemm1)
    // phase2: [64M,96M) xconv f32, [96M,97.1M) params, [100M..) y bf16, wo bf16
    float*  xz     = (float*)(ws);
    __bf16* x_hi   = (__bf16*)(ws + 67108864);
    __bf16* x_lo   = (__bf16*)(ws + 83886080);
    __bf16* wi_hi  = (__bf16*)(ws + 100663296);
    __bf16* wi_lo  = (__bf16*)(ws + 104857600);
    float*  xconv  = (float*)(ws + 67108864);      // reuse (x_hi dead)
    float*  params = (float*)(ws + 100663296);     // reuse (wi_hi dead)
    __bf16* y      = (__bf16*)(ws + 104857600);    // reuse (wi_lo dead)
    __bf16* wo     = (__bf16*)(ws + 121634816);    // +2 MiB -> total ~118 MiB

    const int n_x  = M_ROWS * DMODEL;        // 8388608
    const int n_wi = 2 * DMODEL * DMODEL;    // 2097152
    const int n_wo = DMODEL * DMODEL;        // 1048576

    // 0) precision-split / convert weights & activations
    cvt_split<<<(n_x + 255) / 256, 256, 0, stream>>>(x, x_hi, x_lo, n_x);
    cvt_split<<<(n_wi + 255) / 256, 256, 0, stream>>>(in_proj_w, wi_hi, wi_lo, n_wi);
    cvt_plain<<<(n_wo + 255) / 256, 256, 0, stream>>>(out_proj_w, wo, n_wo);

    // 1) in_proj: xz = x @ in_proj_w^T   (M=8192, N=2048, K=1024), f32-accurate
    gemm_split<<<dim3(2048 / 64, M_ROWS / 128), 256, 0, stream>>>(
        x_hi, x_lo, wi_hi, wi_lo, xz, DMODEL, 2048);

    // 2) causal depthwise conv + SiLU (f32)
    conv_silu_kernel<<<(M_ROWS * DMODEL) / 256, 256, 0, stream>>>(
        xz, conv_w, conv_b, xconv);

    // 3) x_proj (+softplus on delta), f32 VALU
    xproj_kernel<<<M_ROWS / 4, 256, 0, stream>>>(xconv, x_proj_w, params);

    // 4) selective scan + gating epilogue (f32, y emitted bf16)
    scan_kernel<<<dim3(BATCH, DMODEL / 64), 64, 0, stream>>>(
        params, xconv, xz, A_log, D_param, y);

    // 5) out_proj: out = y @ out_proj_w^T  (M=8192, N=1024, K=1024), f32 out
    gemm_bf16<<<dim3(1024 / 64, M_ROWS / 128), 256, 0, stream>>>(
        y, wo, out, DMODEL, 1024);
}

// Round 3
// 717.592 us; speedup vs baseline: 2.6517x; 2.6517x over previous
//
#include <hip/hip_runtime.h>

typedef __bf16 bf16x8 __attribute__((ext_vector_type(8)));
typedef float  f32x4  __attribute__((ext_vector_type(4)));

#define BATCH 4
#define SEQ 2048
#define DMODEL 1024
#define M_ROWS (BATCH * SEQ)      // 8192
#define NCHUNK 32                 // chunks along SEQ
#define CLEN 64                   // steps per chunk (NCHUNK*CLEN == SEQ)

// ---------------------------------------------------------------
// f32 -> (hi, lo) bf16 split:  v ~= hi + lo
// ---------------------------------------------------------------
__global__ __launch_bounds__(256) void cvt_split(
    const float* __restrict__ src, __bf16* __restrict__ hi,
    __bf16* __restrict__ lo, int n)
{
    const int i = blockIdx.x * 256 + threadIdx.x;
    if (i < n) {
        const float v = src[i];
        const __bf16 h = (__bf16)v;
        hi[i] = h;
        lo[i] = (__bf16)(v - (float)h);
    }
}

__global__ __launch_bounds__(256) void cvt_plain(
    const float* __restrict__ src, __bf16* __restrict__ dst, int n)
{
    const int i = blockIdx.x * 256 + threadIdx.x;
    if (i < n) dst[i] = (__bf16)src[i];
}

// ---------------------------------------------------------------
// Split-precision GEMM: C = A @ W^T, f32-accurate via 3x bf16 MFMA.
// Wave tile 32(M) x 64(N); block 128 x 64.
// ---------------------------------------------------------------
__global__ __launch_bounds__(256) void gemm_split(
    const __bf16* __restrict__ Ah, const __bf16* __restrict__ Al,
    const __bf16* __restrict__ Bh, const __bf16* __restrict__ Bl,
    float* __restrict__ C, int K, int N)
{
    const int wave = threadIdx.x >> 6;
    const int lane = threadIdx.x & 63;
    const int m0 = blockIdx.y * 128 + wave * 32;
    const int n0 = blockIdx.x * 64;
    const int qk = (lane >> 4) * 8;
    const int r16 = lane & 15;

    f32x4 acc[2][4] = {};
    const size_t a0 = (size_t)(m0 + r16) * K + qk;
    const size_t a1 = a0 + (size_t)16 * K;
    const size_t b0 = (size_t)(n0 + r16) * K + qk;

    for (int k0 = 0; k0 < K; k0 += 32) {
        bf16x8 ah0 = *(const bf16x8*)(Ah + a0 + k0);
        bf16x8 al0 = *(const bf16x8*)(Al + a0 + k0);
        bf16x8 ah1 = *(const bf16x8*)(Ah + a1 + k0);
        bf16x8 al1 = *(const bf16x8*)(Al + a1 + k0);
#pragma unroll
        for (int i = 0; i < 4; ++i) {
            bf16x8 bh = *(const bf16x8*)(Bh + b0 + (size_t)i * 16 * K + k0);
            bf16x8 bl = *(const bf16x8*)(Bl + b0 + (size_t)i * 16 * K + k0);
            acc[0][i] = __builtin_amdgcn_mfma_f32_16x16x32_bf16(al0, bh, acc[0][i], 0, 0, 0);
            acc[0][i] = __builtin_amdgcn_mfma_f32_16x16x32_bf16(ah0, bl, acc[0][i], 0, 0, 0);
            acc[0][i] = __builtin_amdgcn_mfma_f32_16x16x32_bf16(ah0, bh, acc[0][i], 0, 0, 0);
            acc[1][i] = __builtin_amdgcn_mfma_f32_16x16x32_bf16(al1, bh, acc[1][i], 0, 0, 0);
            acc[1][i] = __builtin_amdgcn_mfma_f32_16x16x32_bf16(ah1, bl, acc[1][i], 0, 0, 0);
            acc[1][i] = __builtin_amdgcn_mfma_f32_16x16x32_bf16(ah1, bh, acc[1][i], 0, 0, 0);
        }
    }

    const int r_off = (lane >> 4) * 4;
#pragma unroll
    for (int s = 0; s < 2; ++s)
#pragma unroll
        for (int i = 0; i < 4; ++i)
#pragma unroll
            for (int r = 0; r < 4; ++r)
                C[(size_t)(m0 + s * 16 + r_off + r) * N + n0 + i * 16 + r16] = acc[s][i][r];
}

// ---------------------------------------------------------------
// Plain bf16 GEMM (final linear out_proj), f32 output.
// ---------------------------------------------------------------
__global__ __launch_bounds__(256) void gemm_bf16(
    const __bf16* __restrict__ A, const __bf16* __restrict__ B,
    float* __restrict__ C, int K, int N)
{
    const int wave = threadIdx.x >> 6;
    const int lane = threadIdx.x & 63;
    const int m0 = blockIdx.y * 128 + wave * 32;
    const int n0 = blockIdx.x * 64;
    const int qk = (lane >> 4) * 8;
    const int r16 = lane & 15;

    f32x4 acc[2][4] = {};
    const size_t a0 = (size_t)(m0 + r16) * K + qk;
    const size_t a1 = a0 + (size_t)16 * K;
    const size_t b0 = (size_t)(n0 + r16) * K + qk;

    for (int k0 = 0; k0 < K; k0 += 32) {
        bf16x8 av0 = *(const bf16x8*)(A + a0 + k0);
        bf16x8 av1 = *(const bf16x8*)(A + a1 + k0);
#pragma unroll
        for (int i = 0; i < 4; ++i) {
            bf16x8 bv = *(const bf16x8*)(B + b0 + (size_t)i * 16 * K + k0);
            acc[0][i] = __builtin_amdgcn_mfma_f32_16x16x32_bf16(av0, bv, acc[0][i], 0, 0, 0);
            acc[1][i] = __builtin_amdgcn_mfma_f32_16x16x32_bf16(av1, bv, acc[1][i], 0, 0, 0);
        }
    }

    const int r_off = (lane >> 4) * 4;
#pragma unroll
    for (int s = 0; s < 2; ++s)
#pragma unroll
        for (int i = 0; i < 4; ++i)
#pragma unroll
            for (int r = 0; r < 4; ++r)
                C[(size_t)(m0 + s * 16 + r_off + r) * N + n0 + i * 16 + r16] = acc[s][i][r];
}

// ---------------------------------------------------------------
// Depthwise causal conv (width 4) + bias + SiLU, f32.
// ---------------------------------------------------------------
__global__ __launch_bounds__(256) void conv_silu_kernel(
    const float* __restrict__ xz,
    const float* __restrict__ conv_w,
    const float* __restrict__ conv_b,
    float* __restrict__ x_conv)
{
    const int idx = blockIdx.x * 256 + threadIdx.x;
    const int d = idx & (DMODEL - 1);
    const int m = idx >> 10;
    const int l = m & (SEQ - 1);

    float acc = conv_b[d];
#pragma unroll
    for (int k = 0; k < 4; ++k) {
        const int ll = l + k - 3;
        if (ll >= 0)
            acc += xz[(size_t)(m + k - 3) * 2048 + d] * conv_w[d * 4 + k];
    }
    x_conv[idx] = acc / (1.f + __expf(-acc));
}

// ---------------------------------------------------------------
// x_proj: P[m][e] = sum_d xc[m][d]*W[e][d], e<33. softplus on e==32.
// ---------------------------------------------------------------
__global__ __launch_bounds__(256) void xproj_kernel(
    const float* __restrict__ xc,
    const float* __restrict__ W,
    float* __restrict__ P)
{
    const int wave = threadIdx.x >> 6;
    const int lane = threadIdx.x & 63;
    const int row = blockIdx.x * 4 + wave;
    const float* xr = xc + (size_t)row * DMODEL;

    float acc[33];
#pragma unroll
    for (int e = 0; e < 33; ++e) acc[e] = 0.f;

    for (int d = lane; d < DMODEL; d += 64) {
        const float xv = xr[d];
#pragma unroll
        for (int e = 0; e < 33; ++e)
            acc[e] += xv * W[e * DMODEL + d];
    }
#pragma unroll
    for (int e = 0; e < 33; ++e) {
        float v = acc[e];
#pragma unroll
        for (int off = 32; off; off >>= 1) v += __shfl_xor(v, off, 64);
        acc[e] = v;
    }
    if (lane == 0) {
        float* out = P + (size_t)row * 33;
        for (int e = 0; e < 32; ++e) out[e] = acc[e];
        const float x = acc[32];
        out[32] = (x > 20.f) ? x : log1pf(expf(x));
    }
}

// ---------------------------------------------------------------
// Chunked parallel scan.
// phase1: per (b,d,chunk) local scan with h0=0 -> h_end (bf16) + S=Σdelta.
// phase2: per (b,d,n) sequential combine over chunks; hbuf becomes h0.
// phase3: local scan seeded with h0, fused y + D-skip + SiLU(z) gating.
// ---------------------------------------------------------------
__global__ __launch_bounds__(256) void scan_phase1(
    const float* __restrict__ P,      // (M,33)
    const float* __restrict__ xc,     // (M,1024)
    const float* __restrict__ A_log,  // (1024,16)
    __bf16* __restrict__ hbuf,        // (B,NCHUNK,1024,16)
    float* __restrict__ S)            // (B,NCHUNK)
{
    const int d = blockIdx.x * 256 + threadIdx.x;
    const int c = blockIdx.y;
    const int b = blockIdx.z;
    const int l0 = c * CLEN;

    __shared__ float buf[CLEN * 33];
    const float* src = P + (size_t)(b * SEQ + l0) * 33;
    for (int idx = threadIdx.x; idx < CLEN * 33; idx += 256)
        buf[idx] = src[idx];
    __syncthreads();

    if (threadIdx.x == 0 && blockIdx.x == 0) {
        float s = 0.f;
        for (int j = 0; j < CLEN; ++j) s += buf[j * 33 + 32];
        S[b * NCHUNK + c] = s;
    }

    float a[16];
#pragma unroll
    for (int n = 0; n < 16; ++n) a[n] = -__expf(A_log[d * 16 + n]);
    float h[16];
#pragma unroll
    for (int n = 0; n < 16; ++n) h[n] = 0.f;

    for (int j = 0; j < CLEN; ++j) {
        const int m = b * SEQ + l0 + j;
        const float xv = xc[(size_t)m * 1024 + d];
        const float* pp = &buf[j * 33];
        const float delta = pp[32];
        const float dx = delta * xv;
#pragma unroll
        for (int n = 0; n < 16; ++n)
            h[n] = __expf(delta * a[n]) * h[n] + dx * pp[n];
    }

    __bf16* hp = hbuf + ((size_t)(b * NCHUNK + c) * 1024 + d) * 16;
#pragma unroll
    for (int n = 0; n < 16; ++n) hp[n] = (__bf16)h[n];
}

__global__ __launch_bounds__(256) void scan_phase2(
    const float* __restrict__ A_log,
    const float* __restrict__ S,
    __bf16* __restrict__ hbuf)
{
    const int n = threadIdx.x & 15;
    const int d = blockIdx.x * 16 + (threadIdx.x >> 4);
    const int b = blockIdx.y;
    const float a = -__expf(A_log[d * 16 + n]);
    float h = 0.f;
    for (int c = 0; c < NCHUNK; ++c) {
        const size_t off = ((size_t)(b * NCHUNK + c) * 1024 + d) * 16 + n;
        const float he = (float)hbuf[off];
        hbuf[off] = (__bf16)h;                       // h_end -> h0 in place
        h = __expf(a * S[b * NCHUNK + c]) * h + he;
    }
}

__global__ __launch_bounds__(256) void scan_phase3(
    const float* __restrict__ P,
    const float* __restrict__ xc,
    const float* __restrict__ xz,     // z at col 1024+d
    const float* __restrict__ A_log,
    const float* __restrict__ Dp,
    const __bf16* __restrict__ hbuf,  // now h0 per chunk
    __bf16* __restrict__ Y)
{
    const int d = blockIdx.x * 256 + threadIdx.x;
    const int c = blockIdx.y;
    const int b = blockIdx.z;
    const int l0 = c * CLEN;

    __shared__ float buf[CLEN * 33];
    const float* src = P + (size_t)(b * SEQ + l0) * 33;
    for (int idx = threadIdx.x; idx < CLEN * 33; idx += 256)
        buf[idx] = src[idx];
    __syncthreads();

    float a[16];
#pragma unroll
    for (int n = 0; n < 16; ++n) a[n] = -__expf(A_log[d * 16 + n]);
    const float Dv = Dp[d];

    const __bf16* hp = hbuf + ((size_t)(b * NCHUNK + c) * 1024 + d) * 16;
    float h[16];
#pragma unroll
    for (int n = 0; n < 16; ++n) h[n] = (float)hp[n];

    for (int j = 0; j < CLEN; ++j) {
        const int m = b * SEQ + l0 + j;
        const float xv = xc[(size_t)m * 1024 + d];
        const float zv = xz[(size_t)m * 2048 + 1024 + d];
        const float* pp = &buf[j * 33];
        const float delta = pp[32];
        const float dx = delta * xv;
        float y = 0.f;
#pragma unroll
        for (int n = 0; n < 16; ++n) {
            h[n] = __expf(delta * a[n]) * h[n] + dx * pp[n];
            y += h[n] * pp[16 + n];
        }
        y += Dv * xv;
        const float sz = zv / (1.f + __expf(-zv));
        Y[(size_t)m * 1024 + d] = (__bf16)(y * sz);
    }
}

// ---------------------------------------------------------------
extern "C" void kernel_launch(void* const* d_in, const int* in_sizes, int n_in,
                              void* d_out, int out_size, void* d_ws, size_t ws_size,
                              hipStream_t stream) {
    const float* x          = (const float*)d_in[0];
    const float* in_proj_w  = (const float*)d_in[1];
    const float* conv_w     = (const float*)d_in[2];
    const float* conv_b     = (const float*)d_in[3];
    const float* x_proj_w   = (const float*)d_in[4];
    const float* A_log      = (const float*)d_in[5];
    const float* D_param    = (const float*)d_in[6];
    const float* out_proj_w = (const float*)d_in[7];
    float* out = (float*)d_out;

    char* ws = (char*)d_ws;
    // phase A (cvt+gemm1): xz[0,64M) x_hi[64M,80M) x_lo[80M,96M)
    //                      wi_hi[96M,100M) wi_lo[100M,104M) wo[120M,122M)
    // phase B (post-gemm1): xconv[64M,96M) params[96M,97.03M)
    //                       hbuf[97.03M,101.03M) S[101.03M+..] y[104M,120M)
    float*  xz     = (float*)(ws);
    __bf16* x_hi   = (__bf16*)(ws + 67108864);
    __bf16* x_lo   = (__bf16*)(ws + 83886080);
    __bf16* wi_hi  = (__bf16*)(ws + 100663296);
    __bf16* wi_lo  = (__bf16*)(ws + 104857600);
    float*  xconv  = (float*)(ws + 67108864);              // over x_hi/x_lo
    float*  params = (float*)(ws + 100663296);             // over wi_hi, 1.04 MiB
    __bf16* hbuf   = (__bf16*)(ws + 101744640);            // 4 MiB, over wi tail
    float*  Sbuf   = (float*)(ws + 105938944);             // 512 B
    __bf16* y      = (__bf16*)(ws + 109051904);            // 16 MiB
    __bf16* wo     = (__bf16*)(ws + 125829120);            // 2 MiB -> end ~122 MiB

    const int n_x  = M_ROWS * DMODEL;
    const int n_wi = 2 * DMODEL * DMODEL;
    const int n_wo = DMODEL * DMODEL;

    cvt_split<<<(n_x + 255) / 256, 256, 0, stream>>>(x, x_hi, x_lo, n_x);
    cvt_split<<<(n_wi + 255) / 256, 256, 0, stream>>>(in_proj_w, wi_hi, wi_lo, n_wi);
    cvt_plain<<<(n_wo + 255) / 256, 256, 0, stream>>>(out_proj_w, wo, n_wo);

    // 1) in_proj (M=8192,N=2048,K=1024), f32-accurate
    gemm_split<<<dim3(2048 / 64, M_ROWS / 128), 256, 0, stream>>>(
        x_hi, x_lo, wi_hi, wi_lo, xz, DMODEL, 2048);

    // 2) conv + SiLU
    conv_silu_kernel<<<(M_ROWS * DMODEL) / 256, 256, 0, stream>>>(
        xz, conv_w, conv_b, xconv);

    // 3) x_proj (+softplus)
    xproj_kernel<<<M_ROWS / 4, 256, 0, stream>>>(xconv, x_proj_w, params);

    // 4) chunked parallel scan
    scan_phase1<<<dim3(DMODEL / 256, NCHUNK, BATCH), 256, 0, stream>>>(
        params, xconv, A_log, hbuf, Sbuf);
    scan_phase2<<<dim3(DMODEL / 16, BATCH), 256, 0, stream>>>(
        A_log, Sbuf, hbuf);
    scan_phase3<<<dim3(DMODEL / 256, NCHUNK, BATCH), 256, 0, stream>>>(
        params, xconv, xz, A_log, D_param, hbuf, y);

    // 5) out_proj (M=8192,N=1024,K=1024)
    gemm_bf16<<<dim3(1024 / 64, M_ROWS / 128), 256, 0, stream>>>(
        y, wo, out, DMODEL, 1024);
}

// Round 5
// 479.287 us; speedup vs baseline: 3.9701x; 1.4972x over previous
//
#include <hip/hip_runtime.h>

typedef __bf16 bf16x8 __attribute__((ext_vector_type(8)));
typedef float  f32x4  __attribute__((ext_vector_type(4)));

#define BATCH 4
#define SEQ 2048
#define DMODEL 1024
#define M_ROWS (BATCH * SEQ)      // 8192
#define NCHUNK 32
#define CLEN 64

// ---------------------------------------------------------------
// async 16B global -> LDS (lane-linear dest), gfx950
// ---------------------------------------------------------------
__device__ __forceinline__ void gload_lds16(const __bf16* g, __bf16* l) {
    __builtin_amdgcn_global_load_lds(
        (const __attribute__((address_space(1))) void*)g,
        (__attribute__((address_space(3))) void*)l, 16, 0, 0);
}

// ---------------------------------------------------------------
// f32 -> (hi, lo) bf16 split
// ---------------------------------------------------------------
__global__ __launch_bounds__(256) void cvt_split(
    const float* __restrict__ src, __bf16* __restrict__ hi,
    __bf16* __restrict__ lo, int n)
{
    const int i = blockIdx.x * 256 + threadIdx.x;
    if (i < n) {
        const float v = src[i];
        const __bf16 h = (__bf16)v;
        hi[i] = h;
        lo[i] = (__bf16)(v - (float)h);
    }
}

__global__ __launch_bounds__(256) void cvt_plain(
    const float* __restrict__ src, __bf16* __restrict__ dst, int n)
{
    const int i = blockIdx.x * 256 + threadIdx.x;
    if (i < n) dst[i] = (__bf16)src[i];
}

// ---------------------------------------------------------------
// m97-style tiled GEMM: C[m][n] = sum_k A[m][k]*W[n][k].
// 128x128 tile, BK=32, 4 waves, each wave a 64x64 quadrant (4x4 accs).
// LDS staged in MFMA-fragment-linear order via global_load_lds(16B):
//   sub-tile s (16 rows x 32 k = 512 elems): lane l holds row 16s+(l&15),
//   k-offset (l>>4)*8, stored at s*512 + l*8 elements.   [FIXED: was *1024]
// SPLIT: f32-accurate via Al*Bh + Ah*Bl + Ah*Bh (3x bf16 MFMA).
// ---------------------------------------------------------------
template <bool SPLIT>
__global__ __launch_bounds__(256) void gemm_tile(
    const __bf16* __restrict__ Ah, const __bf16* __restrict__ Al,
    const __bf16* __restrict__ Bh, const __bf16* __restrict__ Bl,
    float* __restrict__ C, int K, int N)
{
    constexpr int TILE_ELEMS = 128 * 32;                // 4096
    __shared__ alignas(16) __bf16 smem[SPLIT ? 4 * TILE_ELEMS : 2 * TILE_ELEMS];

    const int lane = threadIdx.x & 63;
    const int wave = threadIdx.x >> 6;
    const int bm = blockIdx.y * 128;
    const int bn = blockIdx.x * 128;
    const int sub_r = lane & 15;
    const int kq = (lane >> 4) * 8;

    __bf16* sAh = smem;
    __bf16* sAl = smem + TILE_ELEMS;                    // SPLIT only
    __bf16* sBh = smem + (SPLIT ? 2 : 1) * TILE_ELEMS;
    __bf16* sBl = smem + 3 * TILE_ELEMS;                // SPLIT only

    f32x4 acc[4][4] = {};

    const int NSTAGE = SPLIT ? 32 : 16;
    const int mq = (wave & 1) * 4;    // A sub-tile base for this wave
    const int nq = (wave >> 1) * 4;   // B sub-tile base

    for (int k0 = 0; k0 < K; k0 += 32) {
        // ---- stage: global -> LDS, fragment-linear ----
        for (int i = wave; i < NSTAGE; i += 4) {
            const int buf = i >> 3;   // SPLIT: 0=Ah 1=Al 2=Bh 3=Bl ; else 0=A 1=B
            const int s = i & 7;
            const bool isA = SPLIT ? (buf < 2) : (buf == 0);
            const int row = (isA ? bm : bn) + s * 16 + sub_r;
            const __bf16* base;
            if (SPLIT)
                base = (buf == 0) ? Ah : (buf == 1) ? Al : (buf == 2) ? Bh : Bl;
            else
                base = (buf == 0) ? Ah : Bh;
            gload_lds16(base + (size_t)row * K + k0 + kq,
                        smem + buf * TILE_ELEMS + s * 512 + lane * 8);
        }
        __syncthreads();   // drains vmcnt before any wave reads LDS

        // ---- compute ----
        bf16x8 bh[4], bl[4];
#pragma unroll
        for (int ni = 0; ni < 4; ++ni) {
            bh[ni] = *(const bf16x8*)(sBh + (nq + ni) * 512 + lane * 8);
            if (SPLIT)
                bl[ni] = *(const bf16x8*)(sBl + (nq + ni) * 512 + lane * 8);
        }
#pragma unroll
        for (int mi = 0; mi < 4; ++mi) {
            bf16x8 ah = *(const bf16x8*)(sAh + (mq + mi) * 512 + lane * 8);
            if (SPLIT) {
                bf16x8 al = *(const bf16x8*)(sAl + (mq + mi) * 512 + lane * 8);
#pragma unroll
                for (int ni = 0; ni < 4; ++ni) {
                    acc[mi][ni] = __builtin_amdgcn_mfma_f32_16x16x32_bf16(al, bh[ni], acc[mi][ni], 0, 0, 0);
                    acc[mi][ni] = __builtin_amdgcn_mfma_f32_16x16x32_bf16(ah, bl[ni], acc[mi][ni], 0, 0, 0);
                    acc[mi][ni] = __builtin_amdgcn_mfma_f32_16x16x32_bf16(ah, bh[ni], acc[mi][ni], 0, 0, 0);
                }
            } else {
#pragma unroll
                for (int ni = 0; ni < 4; ++ni)
                    acc[mi][ni] = __builtin_amdgcn_mfma_f32_16x16x32_bf16(ah, bh[ni], acc[mi][ni], 0, 0, 0);
            }
        }
        __syncthreads();   // protect LDS before next stage
    }

    // ---- epilogue: D layout row=(l>>4)*4+r, col=l&15 ----
    const int r_off = (lane >> 4) * 4;
    const int cc = lane & 15;
#pragma unroll
    for (int mi = 0; mi < 4; ++mi) {
        const int row0 = bm + (wave & 1) * 64 + mi * 16 + r_off;
#pragma unroll
        for (int ni = 0; ni < 4; ++ni) {
            const int col = bn + (wave >> 1) * 64 + ni * 16 + cc;
#pragma unroll
            for (int r = 0; r < 4; ++r)
                C[(size_t)(row0 + r) * N + col] = acc[mi][ni][r];
        }
    }
}

// ---------------------------------------------------------------
// Depthwise causal conv (width 4) + bias + SiLU, f32.
// ---------------------------------------------------------------
__global__ __launch_bounds__(256) void conv_silu_kernel(
    const float* __restrict__ xz,
    const float* __restrict__ conv_w,
    const float* __restrict__ conv_b,
    float* __restrict__ x_conv)
{
    const int idx = blockIdx.x * 256 + threadIdx.x;
    const int d = idx & (DMODEL - 1);
    const int m = idx >> 10;
    const int l = m & (SEQ - 1);

    float acc = conv_b[d];
#pragma unroll
    for (int k = 0; k < 4; ++k) {
        const int ll = l + k - 3;
        if (ll >= 0)
            acc += xz[(size_t)(m + k - 3) * 2048 + d] * conv_w[d * 4 + k];
    }
    x_conv[idx] = acc / (1.f + __expf(-acc));
}

// ---------------------------------------------------------------
// x_proj: P[m][e] = sum_d xc[m][d]*W[e][d], e<33. softplus on e==32.
// ---------------------------------------------------------------
__global__ __launch_bounds__(256) void xproj_kernel(
    const float* __restrict__ xc,
    const float* __restrict__ W,
    float* __restrict__ P)
{
    const int wave = threadIdx.x >> 6;
    const int lane = threadIdx.x & 63;
    const int row = blockIdx.x * 4 + wave;
    const float* xr = xc + (size_t)row * DMODEL;

    float acc[33];
#pragma unroll
    for (int e = 0; e < 33; ++e) acc[e] = 0.f;

    for (int d = lane; d < DMODEL; d += 64) {
        const float xv = xr[d];
#pragma unroll
        for (int e = 0; e < 33; ++e)
            acc[e] += xv * W[e * DMODEL + d];
    }
#pragma unroll
    for (int e = 0; e < 33; ++e) {
        float v = acc[e];
#pragma unroll
        for (int off = 32; off; off >>= 1) v += __shfl_xor(v, off, 64);
        acc[e] = v;
    }
    if (lane == 0) {
        float* out = P + (size_t)row * 33;
        for (int e = 0; e < 32; ++e) out[e] = acc[e];
        const float x = acc[32];
        out[32] = (x > 20.f) ? x : log1pf(expf(x));
    }
}

// ---------------------------------------------------------------
// Chunked parallel scan (3 phases).
// ---------------------------------------------------------------
__global__ __launch_bounds__(256) void scan_phase1(
    const float* __restrict__ P,
    const float* __restrict__ xc,
    const float* __restrict__ A_log,
    __bf16* __restrict__ hbuf,
    float* __restrict__ S)
{
    const int d = blockIdx.x * 256 + threadIdx.x;
    const int c = blockIdx.y;
    const int b = blockIdx.z;
    const int l0 = c * CLEN;

    __shared__ float buf[CLEN * 33];
    const float* src = P + (size_t)(b * SEQ + l0) * 33;
    for (int idx = threadIdx.x; idx < CLEN * 33; idx += 256)
        buf[idx] = src[idx];
    __syncthreads();

    if (threadIdx.x == 0 && blockIdx.x == 0) {
        float s = 0.f;
        for (int j = 0; j < CLEN; ++j) s += buf[j * 33 + 32];
        S[b * NCHUNK + c] = s;
    }

    float a[16];
#pragma unroll
    for (int n = 0; n < 16; ++n) a[n] = -__expf(A_log[d * 16 + n]);
    float h[16];
#pragma unroll
    for (int n = 0; n < 16; ++n) h[n] = 0.f;

    for (int j = 0; j < CLEN; ++j) {
        const int m = b * SEQ + l0 + j;
        const float xv = xc[(size_t)m * 1024 + d];
        const float* pp = &buf[j * 33];
        const float delta = pp[32];
        const float dx = delta * xv;
#pragma unroll
        for (int n = 0; n < 16; ++n)
            h[n] = __expf(delta * a[n]) * h[n] + dx * pp[n];
    }

    __bf16* hp = hbuf + ((size_t)(b * NCHUNK + c) * 1024 + d) * 16;
#pragma unroll
    for (int n = 0; n < 16; ++n) hp[n] = (__bf16)h[n];
}

__global__ __launch_bounds__(256) void scan_phase2(
    const float* __restrict__ A_log,
    const float* __restrict__ S,
    __bf16* __restrict__ hbuf)
{
    const int n = threadIdx.x & 15;
    const int d = blockIdx.x * 16 + (threadIdx.x >> 4);
    const int b = blockIdx.y;
    const float a = -__expf(A_log[d * 16 + n]);
    float h = 0.f;
    for (int c = 0; c < NCHUNK; ++c) {
        const size_t off = ((size_t)(b * NCHUNK + c) * 1024 + d) * 16 + n;
        const float he = (float)hbuf[off];
        hbuf[off] = (__bf16)h;
        h = __expf(a * S[b * NCHUNK + c]) * h + he;
    }
}

__global__ __launch_bounds__(256) void scan_phase3(
    const float* __restrict__ P,
    const float* __restrict__ xc,
    const float* __restrict__ xz,
    const float* __restrict__ A_log,
    const float* __restrict__ Dp,
    const __bf16* __restrict__ hbuf,
    __bf16* __restrict__ Y)
{
    const int d = blockIdx.x * 256 + threadIdx.x;
    const int c = blockIdx.y;
    const int b = blockIdx.z;
    const int l0 = c * CLEN;

    __shared__ float buf[CLEN * 33];
    const float* src = P + (size_t)(b * SEQ + l0) * 33;
    for (int idx = threadIdx.x; idx < CLEN * 33; idx += 256)
        buf[idx] = src[idx];
    __syncthreads();

    float a[16];
#pragma unroll
    for (int n = 0; n < 16; ++n) a[n] = -__expf(A_log[d * 16 + n]);
    const float Dv = Dp[d];

    const __bf16* hp = hbuf + ((size_t)(b * NCHUNK + c) * 1024 + d) * 16;
    float h[16];
#pragma unroll
    for (int n = 0; n < 16; ++n) h[n] = (float)hp[n];

    for (int j = 0; j < CLEN; ++j) {
        const int m = b * SEQ + l0 + j;
        const float xv = xc[(size_t)m * 1024 + d];
        const float zv = xz[(size_t)m * 2048 + 1024 + d];
        const float* pp = &buf[j * 33];
        const float delta = pp[32];
        const float dx = delta * xv;
        float y = 0.f;
#pragma unroll
        for (int n = 0; n < 16; ++n) {
            h[n] = __expf(delta * a[n]) * h[n] + dx * pp[n];
            y += h[n] * pp[16 + n];
        }
        y += Dv * xv;
        const float sz = zv / (1.f + __expf(-zv));
        Y[(size_t)m * 1024 + d] = (__bf16)(y * sz);
    }
}

// ---------------------------------------------------------------
extern "C" void kernel_launch(void* const* d_in, const int* in_sizes, int n_in,
                              void* d_out, int out_size, void* d_ws, size_t ws_size,
                              hipStream_t stream) {
    const float* x          = (const float*)d_in[0];
    const float* in_proj_w  = (const float*)d_in[1];
    const float* conv_w     = (const float*)d_in[2];
    const float* conv_b     = (const float*)d_in[3];
    const float* x_proj_w   = (const float*)d_in[4];
    const float* A_log      = (const float*)d_in[5];
    const float* D_param    = (const float*)d_in[6];
    const float* out_proj_w = (const float*)d_in[7];
    float* out = (float*)d_out;

    char* ws = (char*)d_ws;
    float*  xz     = (float*)(ws);
    __bf16* x_hi   = (__bf16*)(ws + 67108864);
    __bf16* x_lo   = (__bf16*)(ws + 83886080);
    __bf16* wi_hi  = (__bf16*)(ws + 100663296);
    __bf16* wi_lo  = (__bf16*)(ws + 104857600);
    float*  xconv  = (float*)(ws + 67108864);
    float*  params = (float*)(ws + 100663296);
    __bf16* hbuf   = (__bf16*)(ws + 101744640);
    float*  Sbuf   = (float*)(ws + 105938944);
    __bf16* y      = (__bf16*)(ws + 109051904);
    __bf16* wo     = (__bf16*)(ws + 125829120);

    const int n_x  = M_ROWS * DMODEL;
    const int n_wi = 2 * DMODEL * DMODEL;
    const int n_wo = DMODEL * DMODEL;

    cvt_split<<<(n_x + 255) / 256, 256, 0, stream>>>(x, x_hi, x_lo, n_x);
    cvt_split<<<(n_wi + 255) / 256, 256, 0, stream>>>(in_proj_w, wi_hi, wi_lo, n_wi);
    cvt_plain<<<(n_wo + 255) / 256, 256, 0, stream>>>(out_proj_w, wo, n_wo);

    // 1) in_proj (M=8192,N=2048,K=1024), f32-accurate split
    gemm_tile<true><<<dim3(2048 / 128, M_ROWS / 128), 256, 0, stream>>>(
        x_hi, x_lo, wi_hi, wi_lo, xz, DMODEL, 2048);

    // 2) conv + SiLU
    conv_silu_kernel<<<(M_ROWS * DMODEL) / 256, 256, 0, stream>>>(
        xz, conv_w, conv_b, xconv);

    // 3) x_proj (+softplus)
    xproj_kernel<<<M_ROWS / 4, 256, 0, stream>>>(xconv, x_proj_w, params);

    // 4) chunked parallel scan
    scan_phase1<<<dim3(DMODEL / 256, NCHUNK, BATCH), 256, 0, stream>>>(
        params, xconv, A_log, hbuf, Sbuf);
    scan_phase2<<<dim3(DMODEL / 16, BATCH), 256, 0, stream>>>(
        A_log, Sbuf, hbuf);
    scan_phase3<<<dim3(DMODEL / 256, NCHUNK, BATCH), 256, 0, stream>>>(
        params, xconv, xz, A_log, D_param, hbuf, y);

    // 5) out_proj (M=8192,N=1024,K=1024), plain bf16
    gemm_tile<false><<<dim3(1024 / 128, M_ROWS / 128), 256, 0, stream>>>(
        y, nullptr, wo, nullptr, out, DMODEL, 1024);
}

// Round 6
// 453.924 us; speedup vs baseline: 4.1920x; 1.0559x over previous
//
#include <hip/hip_runtime.h>

typedef __bf16 bf16x8 __attribute__((ext_vector_type(8)));
typedef __bf16 bf16x4 __attribute__((ext_vector_type(4)));
typedef float  f32x4  __attribute__((ext_vector_type(4)));

#define BATCH 4
#define SEQ 2048
#define DMODEL 1024
#define M_ROWS (BATCH * SEQ)      // 8192
#define NCHUNK 32
#define CLEN 64

// ---------------------------------------------------------------
// async 16B global -> LDS, gfx950
// ---------------------------------------------------------------
__device__ __forceinline__ void gload_lds16(const __bf16* g, __bf16* l) {
    __builtin_amdgcn_global_load_lds(
        (const __attribute__((address_space(1))) void*)g,
        (__attribute__((address_space(3))) void*)l, 16, 0, 0);
}

// ---------------------------------------------------------------
// One conversion kernel for all three weight/activation preps.
// 4 elems per thread, float4 in, bf16x4 out.
// ---------------------------------------------------------------
#define GX (M_ROWS * DMODEL / 4)          // 2097152 groups (x split)
#define GW (2 * DMODEL * DMODEL / 4)      //  524288 groups (wi split)
#define GO (DMODEL * DMODEL / 4)          //  262144 groups (wo plain)

__global__ __launch_bounds__(256) void cvt_all(
    const float* __restrict__ x, const float* __restrict__ wi,
    const float* __restrict__ wo,
    __bf16* __restrict__ x_hi, __bf16* __restrict__ x_lo,
    __bf16* __restrict__ wi_hi, __bf16* __restrict__ wi_lo,
    __bf16* __restrict__ wo_b)
{
    const int g = blockIdx.x * 256 + threadIdx.x;
    if (g < GX + GW) {
        const float* src = (g < GX) ? x : wi;
        __bf16* dh = (g < GX) ? x_hi : wi_hi;
        __bf16* dl = (g < GX) ? x_lo : wi_lo;
        const int i = (g < GX) ? g : g - GX;
        const f32x4 v = *(const f32x4*)(src + (size_t)i * 4);
        bf16x4 h, l;
#pragma unroll
        for (int j = 0; j < 4; ++j) {
            h[j] = (__bf16)v[j];
            l[j] = (__bf16)(v[j] - (float)h[j]);
        }
        *(bf16x4*)(dh + (size_t)i * 4) = h;
        *(bf16x4*)(dl + (size_t)i * 4) = l;
    } else {
        const int i = g - GX - GW;
        const f32x4 v = *(const f32x4*)(wo + (size_t)i * 4);
        bf16x4 o;
#pragma unroll
        for (int j = 0; j < 4; ++j) o[j] = (__bf16)v[j];
        *(bf16x4*)(wo_b + (size_t)i * 4) = o;
    }
}

// ---------------------------------------------------------------
// Tiled GEMM: C[m][n] = sum_k A[m][k]*W[n][k].
// 128x128 tile, BK=32, 4 waves, each a 64x64 quadrant (4x4 accs).
// LDS in MFMA-fragment-linear order (sub-tile = 16 rows x 32 k = 512
// elems; lane l holds row 16s+(l&15), k-off (l>>4)*8, at s*512+l*8).
// Staging is wave-static & fully unrolled:
//   SPLIT: wave w stages matrix w (0=Ah 1=Al 2=Bh 3=Bl), s=0..7.
//   plain: waves 0,1 stage A halves; 2,3 stage B halves; s'=0..3.
// SPLIT: f32-accurate via Al*Bh + Ah*Bl + Ah*Bh.
// ---------------------------------------------------------------
template <bool SPLIT>
__global__ __launch_bounds__(256) void gemm_tile(
    const __bf16* __restrict__ Ah, const __bf16* __restrict__ Al,
    const __bf16* __restrict__ Bh, const __bf16* __restrict__ Bl,
    float* __restrict__ C, int K, int N)
{
    constexpr int TILE_ELEMS = 128 * 32;                // 4096
    __shared__ alignas(16) __bf16 smem[SPLIT ? 4 * TILE_ELEMS : 2 * TILE_ELEMS];

    const int lane = threadIdx.x & 63;
    const int wave = threadIdx.x >> 6;
    const int bm = blockIdx.y * 128;
    const int bn = blockIdx.x * 128;
    const int sub_r = lane & 15;
    const int kq = (lane >> 4) * 8;

    __bf16* sAh = smem;
    __bf16* sAl = smem + TILE_ELEMS;                    // SPLIT only
    __bf16* sBh = smem + (SPLIT ? 2 : 1) * TILE_ELEMS;
    __bf16* sBl = smem + 3 * TILE_ELEMS;                // SPLIT only

    // ---- wave-static staging setup ----
    const __bf16* sbase;
    int rbase;
    __bf16* sdst;
    if (SPLIT) {
        sbase = (wave == 0) ? Ah : (wave == 1) ? Al : (wave == 2) ? Bh : Bl;
        rbase = (wave < 2) ? bm : bn;
        sdst  = smem + wave * TILE_ELEMS + lane * 8;
    } else {
        sbase = (wave < 2) ? Ah : Bh;
        rbase = ((wave < 2) ? bm : bn) + (wave & 1) * 64;
        sdst  = smem + (wave >> 1) * TILE_ELEMS + (wave & 1) * 2048 + lane * 8;
    }
    const __bf16* gsrc = sbase + (size_t)(rbase + sub_r) * K + kq;

    f32x4 acc[4][4] = {};
    const int mq = (wave & 1) * 4;
    const int nq = (wave >> 1) * 4;

    for (int k0 = 0; k0 < K; k0 += 32) {
        // ---- stage ----
        if (SPLIT) {
#pragma unroll
            for (int s = 0; s < 8; ++s)
                gload_lds16(gsrc + (size_t)s * 16 * K + k0, sdst + s * 512);
        } else {
#pragma unroll
            for (int s = 0; s < 4; ++s)
                gload_lds16(gsrc + (size_t)s * 16 * K + k0, sdst + s * 512);
        }
        __syncthreads();

        // ---- compute ----
        bf16x8 bh[4], bl[4];
#pragma unroll
        for (int ni = 0; ni < 4; ++ni) {
            bh[ni] = *(const bf16x8*)(sBh + (nq + ni) * 512 + lane * 8);
            if (SPLIT)
                bl[ni] = *(const bf16x8*)(sBl + (nq + ni) * 512 + lane * 8);
        }
#pragma unroll
        for (int mi = 0; mi < 4; ++mi) {
            bf16x8 ah = *(const bf16x8*)(sAh + (mq + mi) * 512 + lane * 8);
            if (SPLIT) {
                bf16x8 al = *(const bf16x8*)(sAl + (mq + mi) * 512 + lane * 8);
#pragma unroll
                for (int ni = 0; ni < 4; ++ni) {
                    acc[mi][ni] = __builtin_amdgcn_mfma_f32_16x16x32_bf16(al, bh[ni], acc[mi][ni], 0, 0, 0);
                    acc[mi][ni] = __builtin_amdgcn_mfma_f32_16x16x32_bf16(ah, bl[ni], acc[mi][ni], 0, 0, 0);
                    acc[mi][ni] = __builtin_amdgcn_mfma_f32_16x16x32_bf16(ah, bh[ni], acc[mi][ni], 0, 0, 0);
                }
            } else {
#pragma unroll
                for (int ni = 0; ni < 4; ++ni)
                    acc[mi][ni] = __builtin_amdgcn_mfma_f32_16x16x32_bf16(ah, bh[ni], acc[mi][ni], 0, 0, 0);
            }
        }
        __syncthreads();
    }

    // ---- epilogue: D layout row=(l>>4)*4+r, col=l&15 ----
    const int r_off = (lane >> 4) * 4;
    const int cc = lane & 15;
#pragma unroll
    for (int mi = 0; mi < 4; ++mi) {
        const int row0 = bm + (wave & 1) * 64 + mi * 16 + r_off;
#pragma unroll
        for (int ni = 0; ni < 4; ++ni) {
            const int col = bn + (wave >> 1) * 64 + ni * 16 + cc;
#pragma unroll
            for (int r = 0; r < 4; ++r)
                C[(size_t)(row0 + r) * N + col] = acc[mi][ni][r];
        }
    }
}

// ---------------------------------------------------------------
// Fused depthwise causal conv(4)+bias+SiLU  ->  x_proj(+softplus).
// One wave per row m; conv computed on the fly, x_conv stored once,
// 33 projection dot-products accumulated in-register.
// ---------------------------------------------------------------
__global__ __launch_bounds__(256) void conv_xproj_kernel(
    const float* __restrict__ xz,
    const float* __restrict__ conv_w,
    const float* __restrict__ conv_b,
    const float* __restrict__ Wx,     // (33,1024)
    float* __restrict__ x_conv,
    float* __restrict__ P)            // (M,33)
{
    const int wave = threadIdx.x >> 6;
    const int lane = threadIdx.x & 63;
    const int m = blockIdx.x * 4 + wave;
    const int l = m & (SEQ - 1);

    float acc[33];
#pragma unroll
    for (int e = 0; e < 33; ++e) acc[e] = 0.f;

    for (int d = lane; d < DMODEL; d += 64) {
        float cacc = conv_b[d];
#pragma unroll
        for (int k = 0; k < 4; ++k) {
            const int ll = l + k - 3;
            if (ll >= 0)
                cacc += xz[(size_t)(m + k - 3) * 2048 + d] * conv_w[d * 4 + k];
        }
        const float xc = cacc / (1.f + __expf(-cacc));   // SiLU
        x_conv[(size_t)m * DMODEL + d] = xc;
#pragma unroll
        for (int e = 0; e < 33; ++e)
            acc[e] += xc * Wx[e * DMODEL + d];
    }
#pragma unroll
    for (int e = 0; e < 33; ++e) {
        float v = acc[e];
#pragma unroll
        for (int off = 32; off; off >>= 1) v += __shfl_xor(v, off, 64);
        acc[e] = v;
    }
    if (lane == 0) {
        float* out = P + (size_t)m * 33;
        for (int e = 0; e < 32; ++e) out[e] = acc[e];
        const float x = acc[32];
        out[32] = (x > 20.f) ? x : log1pf(expf(x));      // softplus
    }
}

// ---------------------------------------------------------------
// Chunked parallel scan (3 phases).
// ---------------------------------------------------------------
__global__ __launch_bounds__(256) void scan_phase1(
    const float* __restrict__ P,
    const float* __restrict__ xc,
    const float* __restrict__ A_log,
    __bf16* __restrict__ hbuf,
    float* __restrict__ S)
{
    const int d = blockIdx.x * 256 + threadIdx.x;
    const int c = blockIdx.y;
    const int b = blockIdx.z;
    const int l0 = c * CLEN;

    __shared__ float buf[CLEN * 33];
    const float* src = P + (size_t)(b * SEQ + l0) * 33;
    for (int idx = threadIdx.x; idx < CLEN * 33; idx += 256)
        buf[idx] = src[idx];
    __syncthreads();

    if (threadIdx.x == 0 && blockIdx.x == 0) {
        float s = 0.f;
        for (int j = 0; j < CLEN; ++j) s += buf[j * 33 + 32];
        S[b * NCHUNK + c] = s;
    }

    float a[16];
#pragma unroll
    for (int n = 0; n < 16; ++n) a[n] = -__expf(A_log[d * 16 + n]);
    float h[16];
#pragma unroll
    for (int n = 0; n < 16; ++n) h[n] = 0.f;

    for (int j = 0; j < CLEN; ++j) {
        const int m = b * SEQ + l0 + j;
        const float xv = xc[(size_t)m * 1024 + d];
        const float* pp = &buf[j * 33];
        const float delta = pp[32];
        const float dx = delta * xv;
#pragma unroll
        for (int n = 0; n < 16; ++n)
            h[n] = __expf(delta * a[n]) * h[n] + dx * pp[n];
    }

    __bf16* hp = hbuf + ((size_t)(b * NCHUNK + c) * 1024 + d) * 16;
#pragma unroll
    for (int n = 0; n < 16; ++n) hp[n] = (__bf16)h[n];
}

__global__ __launch_bounds__(256) void scan_phase2(
    const float* __restrict__ A_log,
    const float* __restrict__ S,
    __bf16* __restrict__ hbuf)
{
    const int n = threadIdx.x & 15;
    const int d = blockIdx.x * 16 + (threadIdx.x >> 4);
    const int b = blockIdx.y;
    const float a = -__expf(A_log[d * 16 + n]);
    float h = 0.f;
    for (int c = 0; c < NCHUNK; ++c) {
        const size_t off = ((size_t)(b * NCHUNK + c) * 1024 + d) * 16 + n;
        const float he = (float)hbuf[off];
        hbuf[off] = (__bf16)h;
        h = __expf(a * S[b * NCHUNK + c]) * h + he;
    }
}

__global__ __launch_bounds__(256) void scan_phase3(
    const float* __restrict__ P,
    const float* __restrict__ xc,
    const float* __restrict__ xz,
    const float* __restrict__ A_log,
    const float* __restrict__ Dp,
    const __bf16* __restrict__ hbuf,
    __bf16* __restrict__ Y)
{
    const int d = blockIdx.x * 256 + threadIdx.x;
    const int c = blockIdx.y;
    const int b = blockIdx.z;
    const int l0 = c * CLEN;

    __shared__ float buf[CLEN * 33];
    const float* src = P + (size_t)(b * SEQ + l0) * 33;
    for (int idx = threadIdx.x; idx < CLEN * 33; idx += 256)
        buf[idx] = src[idx];
    __syncthreads();

    float a[16];
#pragma unroll
    for (int n = 0; n < 16; ++n) a[n] = -__expf(A_log[d * 16 + n]);
    const float Dv = Dp[d];

    const __bf16* hp = hbuf + ((size_t)(b * NCHUNK + c) * 1024 + d) * 16;
    float h[16];
#pragma unroll
    for (int n = 0; n < 16; ++n) h[n] = (float)hp[n];

    for (int j = 0; j < CLEN; ++j) {
        const int m = b * SEQ + l0 + j;
        const float xv = xc[(size_t)m * 1024 + d];
        const float zv = xz[(size_t)m * 2048 + 1024 + d];
        const float* pp = &buf[j * 33];
        const float delta = pp[32];
        const float dx = delta * xv;
        float y = 0.f;
#pragma unroll
        for (int n = 0; n < 16; ++n) {
            h[n] = __expf(delta * a[n]) * h[n] + dx * pp[n];
            y += h[n] * pp[16 + n];
        }
        y += Dv * xv;
        const float sz = zv / (1.f + __expf(-zv));
        Y[(size_t)m * 1024 + d] = (__bf16)(y * sz);
    }
}

// ---------------------------------------------------------------
extern "C" void kernel_launch(void* const* d_in, const int* in_sizes, int n_in,
                              void* d_out, int out_size, void* d_ws, size_t ws_size,
                              hipStream_t stream) {
    const float* x          = (const float*)d_in[0];
    const float* in_proj_w  = (const float*)d_in[1];
    const float* conv_w     = (const float*)d_in[2];
    const float* conv_b     = (const float*)d_in[3];
    const float* x_proj_w   = (const float*)d_in[4];
    const float* A_log      = (const float*)d_in[5];
    const float* D_param    = (const float*)d_in[6];
    const float* out_proj_w = (const float*)d_in[7];
    float* out = (float*)d_out;

    char* ws = (char*)d_ws;
    float*  xz     = (float*)(ws);
    __bf16* x_hi   = (__bf16*)(ws + 67108864);
    __bf16* x_lo   = (__bf16*)(ws + 83886080);
    __bf16* wi_hi  = (__bf16*)(ws + 100663296);
    __bf16* wi_lo  = (__bf16*)(ws + 104857600);
    float*  xconv  = (float*)(ws + 67108864);
    float*  params = (float*)(ws + 100663296);
    __bf16* hbuf   = (__bf16*)(ws + 101744640);
    float*  Sbuf   = (float*)(ws + 105938944);
    __bf16* y      = (__bf16*)(ws + 109051904);
    __bf16* wo     = (__bf16*)(ws + 125829120);

    // 0) all dtype conversions in one dispatch
    cvt_all<<<(GX + GW + GO) / 256, 256, 0, stream>>>(
        x, in_proj_w, out_proj_w, x_hi, x_lo, wi_hi, wi_lo, wo);

    // 1) in_proj (M=8192,N=2048,K=1024), f32-accurate split
    gemm_tile<true><<<dim3(2048 / 128, M_ROWS / 128), 256, 0, stream>>>(
        x_hi, x_lo, wi_hi, wi_lo, xz, DMODEL, 2048);

    // 2) fused conv+SiLU+x_proj(+softplus)
    conv_xproj_kernel<<<M_ROWS / 4, 256, 0, stream>>>(
        xz, conv_w, conv_b, x_proj_w, xconv, params);

    // 3) chunked parallel scan
    scan_phase1<<<dim3(DMODEL / 256, NCHUNK, BATCH), 256, 0, stream>>>(
        params, xconv, A_log, hbuf, Sbuf);
    scan_phase2<<<dim3(DMODEL / 16, BATCH), 256, 0, stream>>>(
        A_log, Sbuf, hbuf);
    scan_phase3<<<dim3(DMODEL / 256, NCHUNK, BATCH), 256, 0, stream>>>(
        params, xconv, xz, A_log, D_param, hbuf, y);

    // 4) out_proj (M=8192,N=1024,K=1024), plain bf16
    gemm_tile<false><<<dim3(1024 / 128, M_ROWS / 128), 256, 0, stream>>>(
        y, nullptr, wo, nullptr, out, DMODEL, 1024);
}